// Round 1
// baseline (147.993 us; speedup 1.0000x reference)
//
#include <hip/hip_runtime.h>
#include <math.h>

// EngineOrderFFT via batched Bluestein (chirp-z), replicated from the JAX ref.
// Key simplification: |X| = |exp(-i k_phase) * conv| = |conv[:, :K]| -- the
// final chirp multiply is dropped.
//
// M = 16384 FFT implemented as four-step 128x128:
//   pass1: for each t1, 128-pt FFT over t2, * W_M^{sign*t1*k2}, store [k2][t1]
//   pass2: for each k2, 128-pt FFT over t1, output X[k2 + 128*k1]
// Each workgroup: 16 FFTs x 128 pts, Stockham radix-2 in padded LDS.

static constexpr int Bn   = 64;
static constexpr int Cc   = 8;
static constexpr int Nn   = 8192;
static constexpr int Mm   = 16384;
static constexpr int ROWS = Bn * Cc;   // 512
static constexpr int LDSP = 130;       // padded LDS row stride (float2)

#define PI_F 3.14159265358979323846f
#define TWO_PI_F 6.28318530717958647692f

__device__ __forceinline__ int compute_n(float rpm) {
    // ref: pad = floor((40*60.0/rpm - 1)*8192) in f32; n = L + pad
    return 8192 + (int)floorf((2400.0f / rpm - 1.0f) * 8192.0f);
}

// ---------------- build kernels ----------------

__global__ __launch_bounds__(256) void chirp_build(const float* __restrict__ rpm,
                                                   float2* __restrict__ outT) {
    int gid = blockIdx.x * 256 + threadIdx.x;   // Bn*Mm threads
    int b = gid >> 14;
    int m = gid & (Mm - 1);
    int n = compute_n(rpm[b]);
    int mm = min(m, Mm - m);
    int ph = (mm * mm) % (2 * n);
    float phase = (PI_F * (float)ph) / (float)n;
    float s, c;
    sincosf(phase, &s, &c);
    outT[(size_t)b * Mm + m] = make_float2(c, s);   // exp(+i*b_phase)
}

__global__ __launch_bounds__(256) void build_a(const float* __restrict__ x,
                                               const float* __restrict__ rpm,
                                               float2* __restrict__ out) {
    int gid = blockIdx.x * 256 + threadIdx.x;   // Bn*Mm threads (one per (b,t))
    int b = gid >> 14;
    int t = gid & (Mm - 1);
    if (t >= Nn) {
        float2 z = make_float2(0.f, 0.f);
        #pragma unroll
        for (int ch = 0; ch < Cc; ++ch)
            out[((size_t)(b * Cc + ch)) * Mm + t] = z;
        return;
    }
    int n = compute_n(rpm[b]);
    int ph = (t * t) % (2 * n);
    float phase = (PI_F * (float)ph) / (float)n;
    float s, c;
    sincosf(phase, &s, &c);
    const float4* xp = (const float4*)(x + ((size_t)b * Nn + t) * Cc);
    float4 x0 = xp[0];
    float4 x1 = xp[1];
    float xv[8] = {x0.x, x0.y, x0.z, x0.w, x1.x, x1.y, x1.z, x1.w};
    #pragma unroll
    for (int ch = 0; ch < Cc; ++ch)
        out[((size_t)(b * Cc + ch)) * Mm + t] = make_float2(xv[ch] * c, -xv[ch] * s);
}

// ---------------- 128-pt Stockham core ----------------
// 16 threads per FFT, 16 FFTs per workgroup. Input in bufA[f*LDSP + 0..127],
// natural order; output (natural order) lands in bufB. tw[v] = exp(SIGN*i*pi*v/64).

template<int SIGN>
__device__ __forceinline__ void fft128_core(float2* bufA, float2* bufB,
                                            const float2* tw, int f, int lane) {
    float2* src = bufA + f * LDSP;
    float2* dst = bufB + f * LDSP;
    #pragma unroll
    for (int s = 0; s < 7; ++s) {
        __syncthreads();
        #pragma unroll
        for (int q = 0; q < 4; ++q) {
            int u  = lane + (q << 4);        // butterfly id in [0,64)
            int j  = u >> s;
            int jm = j << s;                 // j*m, < 64
            float2 c0 = src[u];
            float2 c1 = src[u + 64];
            float2 w  = tw[jm];
            float sx = c0.x + c1.x, sy = c0.y + c1.y;
            float dx = c0.x - c1.x, dy = c0.y - c1.y;
            dst[u + jm]            = make_float2(sx, sy);
            dst[u + jm + (1 << s)] = make_float2(w.x * dx - w.y * dy,
                                                 w.x * dy + w.y * dx);
        }
        float2* tswap = src; src = dst; dst = tswap;
    }
    __syncthreads();   // 7 stages (odd) -> result in bufB
}

// ---------------- pass 1 ----------------

template<int SIGN, bool MUL>
__global__ __launch_bounds__(256) void fft_pass1(const float2* __restrict__ in,
                                                 const float2* __restrict__ chirpF,
                                                 float2* __restrict__ out) {
    __shared__ float2 bufA[16 * LDSP];
    __shared__ float2 bufB[16 * LDSP];
    __shared__ float2 twd[64];
    int tid  = threadIdx.x;
    int row  = blockIdx.x >> 3;
    int t1_0 = (blockIdx.x & 7) << 4;
    const float2* rin = in + (size_t)row * Mm;
    const float2* cf  = MUL ? (chirpF + (size_t)(row >> 3) * Mm) : nullptr;

    if (tid < 64) {
        float s, c;
        sincosf(PI_F * (float)tid / 64.0f, &s, &c);
        twd[tid] = make_float2(c, (float)SIGN * s);
    }
    #pragma unroll
    for (int lch = 0; lch < 8; ++lch) {
        int l  = lch * 256 + tid;
        int i  = l & 15, t2 = l >> 4;
        int idx = (t1_0 + i) + (t2 << 7);
        float2 v = rin[idx];
        if (MUL) {
            float2 w = cf[idx];
            v = make_float2(v.x * w.x - v.y * w.y, v.x * w.y + v.y * w.x);
        }
        bufA[i * LDSP + t2] = v;
    }
    int f = tid >> 4, lane = tid & 15;
    fft128_core<SIGN>(bufA, bufB, twd, f, lane);

    float2* rout = out + (size_t)row * Mm;
    #pragma unroll
    for (int lch = 0; lch < 8; ++lch) {
        int l = lch * 256 + tid;
        int i = l & 15, k2 = l >> 4;
        float2 v = bufB[i * LDSP + k2];
        int t1 = t1_0 + i;
        float ang = (float)SIGN * TWO_PI_F * (float)(t1 * k2) * (1.0f / 16384.0f);
        float sw, cw;
        sincosf(ang, &sw, &cw);
        rout[(k2 << 7) + t1] = make_float2(v.x * cw - v.y * sw,
                                           v.x * sw + v.y * cw);
    }
}

// ---------------- pass 2 ----------------

template<int SIGN, bool FINAL>
__global__ __launch_bounds__(256) void fft_pass2(const float2* __restrict__ in,
                                                 float2* __restrict__ out,
                                                 float* __restrict__ outF) {
    __shared__ float2 bufA[16 * LDSP];
    __shared__ float2 bufB[16 * LDSP];
    __shared__ float2 twd[64];
    int tid  = threadIdx.x;
    int row  = blockIdx.x >> 3;
    int k2_0 = (blockIdx.x & 7) << 4;
    const float2* rin = in + (size_t)row * Mm + ((size_t)k2_0 << 7);

    if (tid < 64) {
        float s, c;
        sincosf(PI_F * (float)tid / 64.0f, &s, &c);
        twd[tid] = make_float2(c, (float)SIGN * s);
    }
    #pragma unroll
    for (int lch = 0; lch < 8; ++lch) {
        int l = lch * 256 + tid;
        bufA[(l >> 7) * LDSP + (l & 127)] = rin[l];   // fully coalesced read
    }
    int f = tid >> 4, lane = tid & 15;
    fft128_core<SIGN>(bufA, bufB, twd, f, lane);

    if (!FINAL) {
        float2* rout = out + (size_t)row * Mm;
        #pragma unroll
        for (int lch = 0; lch < 8; ++lch) {
            int l = lch * 256 + tid;
            int i = l & 15, k1 = l >> 4;
            rout[(k2_0 + i) + (k1 << 7)] = bufB[i * LDSP + k1];
        }
    } else {
        // conv magnitude, only k = k2 + 128*k1 < 8192  <=> k1 < 64
        int b = row >> 3, ch = row & 7;
        float* ob = outF + (size_t)b * 8192 * 8 + ch;
        #pragma unroll
        for (int lch = 0; lch < 4; ++lch) {
            int l = lch * 256 + tid;
            int i = l & 15, k1 = l >> 4;        // k1 in [0,64)
            float2 v = bufB[i * LDSP + k1];
            int k = (k2_0 + i) + (k1 << 7);
            ob[(size_t)k * 8] = sqrtf(v.x * v.x + v.y * v.y) * (1.0f / 16384.0f);
        }
    }
}

// ---------------- launch ----------------

extern "C" void kernel_launch(void* const* d_in, const int* in_sizes, int n_in,
                              void* d_out, int out_size, void* d_ws, size_t ws_size,
                              hipStream_t stream) {
    const float* x   = (const float*)d_in[0];
    const float* rpm = (const float*)d_in[1];
    float* outF = (float*)d_out;

    float2* work1  = (float2*)d_ws;                     // 512*16384 float2 (64 MiB)
    float2* work2  = work1 + (size_t)ROWS * Mm;         // 512*16384 float2 (64 MiB)
    float2* chirpF = (float2*)d_out;                    // 64*16384 float2, dead before final pass

    // chirp: build (into work1 rows 0..63) -> fft -> chirpF (parked in d_out)
    chirp_build<<<(Bn * Mm) / 256, 256, 0, stream>>>(rpm, work1);
    fft_pass1<-1, false><<<Bn * 8, 256, 0, stream>>>(work1, nullptr, work2);
    fft_pass2<-1, false><<<Bn * 8, 256, 0, stream>>>(work2, chirpF, nullptr);

    // a = x * exp(-i a_phase), zero-padded to M
    build_a<<<(Bn * Mm) / 256, 256, 0, stream>>>(x, rpm, work1);
    // A = fft(a)
    fft_pass1<-1, false><<<ROWS * 8, 256, 0, stream>>>(work1, nullptr, work2);
    fft_pass2<-1, false><<<ROWS * 8, 256, 0, stream>>>(work2, work1, nullptr);
    // conv = ifft(A * Bf); |conv[:, :8192]| -> out   (1/M folded into magnitude)
    fft_pass1<1, true><<<ROWS * 8, 256, 0, stream>>>(work1, chirpF, work2);
    fft_pass2<1, true><<<ROWS * 8, 256, 0, stream>>>(work2, nullptr, outF);
}

// Round 2
// 125.716 us; speedup vs baseline: 1.1772x; 1.1772x over previous
//
#include <hip/hip_runtime.h>
#include <math.h>

// EngineOrderFFT via batched Bluestein (chirp-z).
// |X| = |conv[:, :K]| (final chirp is unit-modulus -> dropped).
// M = 16384 FFT as four-step 128x128, now fused into 3 data kernels:
//   K1: build a (chirp-modulate x) + FFT over t2 + twiddle -> [k2][t1]
//   K2: FFT over t1 (=forward done) -> *Bhat -> inverse FFT over k1 + twiddle -> [j][k2]
//   K3: inverse FFT over k2 -> |.|/M -> out (k = j + 128*w < 8192)
// plus 2 small chirp-prep kernels (64 rows).

static constexpr int Bn   = 64;
static constexpr int Cc   = 8;
static constexpr int Nn   = 8192;
static constexpr int Mm   = 16384;
static constexpr int ROWS = Bn * Cc;   // 512
static constexpr int LDSP = 130;       // padded LDS row stride (float2)

#define PI_F 3.14159265358979323846f
#define TWO_PI_F 6.28318530717958647692f

__device__ __forceinline__ int compute_n(float rpm) {
    // ref: pad = floor((40*60.0/rpm - 1)*8192) in f32; n = L + pad
    return 8192 + (int)floorf((2400.0f / rpm - 1.0f) * 8192.0f);
}

// ---------------- 128-pt Stockham core ----------------
// 16 threads per FFT, 16 FFTs per workgroup. Input natural order in
// bufA[f*LDSP + 0..127]; result lands in bufB (natural order).
// tw[v] = exp(-i*pi*v/64); SIGN=+1 conjugates on the fly.

template<int SIGN>
__device__ __forceinline__ void fft128_core(float2* bufA, float2* bufB,
                                            const float2* tw, int f, int lane) {
    float2* src = bufA + f * LDSP;
    float2* dst = bufB + f * LDSP;
    #pragma unroll
    for (int s = 0; s < 7; ++s) {
        __syncthreads();
        #pragma unroll
        for (int q = 0; q < 4; ++q) {
            int u  = lane + (q << 4);        // butterfly id in [0,64)
            int j  = u >> s;
            int jm = j << s;                 // j*m, < 64
            float2 c0 = src[u];
            float2 c1 = src[u + 64];
            float2 w  = tw[jm];
            float wy = (SIGN == -1) ? w.y : -w.y;
            float sx = c0.x + c1.x, sy = c0.y + c1.y;
            float dx = c0.x - c1.x, dy = c0.y - c1.y;
            dst[u + jm]            = make_float2(sx, sy);
            dst[u + jm + (1 << s)] = make_float2(w.x * dx - wy * dy,
                                                 w.x * dy + wy * dx);
        }
        float2* tswap = src; src = dst; dst = tswap;
    }
    __syncthreads();   // 7 stages (odd) -> result in bufB
}

__device__ __forceinline__ void load_twiddle(float2* twd, int tid) {
    if (tid < 64) {
        float s, c;
        sincosf(PI_F * (float)tid / 64.0f, &s, &c);
        twd[tid] = make_float2(c, -s);   // exp(-i*pi*tid/64)
    }
}

// ---------------- chirp prep (64 rows) ----------------

// Kc1: build b[t] = exp(+i*pi*(mm^2 mod 2n)/n), FFT over t2, twiddle, -> [k2][t1]
__global__ __launch_bounds__(256) void chirp_pass1(const float* __restrict__ rpm,
                                                   float2* __restrict__ out) {
    __shared__ float2 bufA[16 * LDSP];
    __shared__ float2 bufB[16 * LDSP];
    __shared__ float2 twd[64];
    int tid  = threadIdx.x;
    int b    = blockIdx.x >> 3;
    int t1_0 = (blockIdx.x & 7) << 4;
    int n    = compute_n(rpm[b]);
    int two_n = 2 * n;
    float inv_n = 1.0f / (float)n;

    load_twiddle(twd, tid);
    #pragma unroll
    for (int lch = 0; lch < 8; ++lch) {
        int l  = lch * 256 + tid;
        int i  = l & 15, t2 = l >> 4;
        int t  = (t1_0 + i) + (t2 << 7);
        int mm = min(t, Mm - t);
        int ph = (mm * mm) % two_n;
        float s, c;
        sincosf(PI_F * (float)ph * inv_n, &s, &c);
        bufA[i * LDSP + t2] = make_float2(c, s);
    }
    int f = tid >> 4, lane = tid & 15;
    fft128_core<-1>(bufA, bufB, twd, f, lane);

    float2* rout = out + (size_t)b * Mm;
    #pragma unroll
    for (int lch = 0; lch < 8; ++lch) {
        int l = lch * 256 + tid;
        int i = l & 15, k2 = l >> 4;
        float2 v = bufB[i * LDSP + k2];
        int t1 = t1_0 + i;
        float ang = -TWO_PI_F * (float)(t1 * k2) * (1.0f / 16384.0f);
        float sw, cw;
        sincosf(ang, &sw, &cw);
        rout[(k2 << 7) + t1] = make_float2(v.x * cw - v.y * sw,
                                           v.x * sw + v.y * cw);
    }
}

// Kc2: FFT over t1, write Bhat TRANSPOSED: Bhat[b][k2][k1] = B[k2 + 128*k1]
__global__ __launch_bounds__(256) void chirp_pass2(const float2* __restrict__ in,
                                                   float2* __restrict__ bhat) {
    __shared__ float2 bufA[16 * LDSP];
    __shared__ float2 bufB[16 * LDSP];
    __shared__ float2 twd[64];
    int tid  = threadIdx.x;
    int b    = blockIdx.x >> 3;
    int k2_0 = (blockIdx.x & 7) << 4;
    const float2* rin = in + (size_t)b * Mm + ((size_t)k2_0 << 7);

    load_twiddle(twd, tid);
    #pragma unroll
    for (int lch = 0; lch < 8; ++lch) {
        int l = lch * 256 + tid;
        bufA[(l >> 7) * LDSP + (l & 127)] = rin[l];
    }
    int f = tid >> 4, lane = tid & 15;
    fft128_core<-1>(bufA, bufB, twd, f, lane);

    float2* rout = bhat + (size_t)b * Mm;
    #pragma unroll
    for (int lch = 0; lch < 8; ++lch) {
        int l = lch * 256 + tid;
        int i = l >> 7, k1 = l & 127;     // i = local k2 idx, coalesced over k1
        rout[((size_t)(k2_0 + i) << 7) + k1] = bufB[i * LDSP + k1];
    }
}

// ---------------- K1: build a + forward pass1 ----------------

__global__ __launch_bounds__(256) void k1_build_fft(const float* __restrict__ x,
                                                    const float* __restrict__ rpm,
                                                    float2* __restrict__ out) {
    __shared__ float2 bufA[16 * LDSP];
    __shared__ float2 bufB[16 * LDSP];
    __shared__ float2 twd[64];
    int tid  = threadIdx.x;
    int row  = blockIdx.x >> 3;           // row = b*8 + ch
    int b    = row >> 3, ch = row & 7;
    int t1_0 = (blockIdx.x & 7) << 4;
    int n    = compute_n(rpm[b]);
    int two_n = 2 * n;
    float inv_n = 1.0f / (float)n;
    const float* xb = x + (size_t)b * Nn * Cc + ch;

    load_twiddle(twd, tid);
    #pragma unroll
    for (int lch = 0; lch < 8; ++lch) {
        int l  = lch * 256 + tid;
        int i  = l & 15, t2 = l >> 4;
        int t  = (t1_0 + i) + (t2 << 7);
        float2 v;
        if (t < Nn) {
            float xv = xb[(size_t)t * Cc];
            int ph = (t * t) % two_n;
            float s, c;
            sincosf(PI_F * (float)ph * inv_n, &s, &c);
            v = make_float2(xv * c, -xv * s);
        } else {
            v = make_float2(0.f, 0.f);
        }
        bufA[i * LDSP + t2] = v;
    }
    int f = tid >> 4, lane = tid & 15;
    fft128_core<-1>(bufA, bufB, twd, f, lane);

    float2* rout = out + (size_t)row * Mm;
    #pragma unroll
    for (int lch = 0; lch < 8; ++lch) {
        int l = lch * 256 + tid;
        int i = l & 15, k2 = l >> 4;
        float2 v = bufB[i * LDSP + k2];
        int t1 = t1_0 + i;
        float ang = -TWO_PI_F * (float)(t1 * k2) * (1.0f / 16384.0f);
        float sw, cw;
        sincosf(ang, &sw, &cw);
        rout[(k2 << 7) + t1] = make_float2(v.x * cw - v.y * sw,
                                           v.x * sw + v.y * cw);
    }
}

// ---------------- K2: fwd pass2 + multiply + inverse pass1 ----------------
// In : A1 layout [k2][t1] (from K1). Block owns k2 in [k2_0,k2_0+16), all t1.
// FFT over t1 -> X[k2][k1]; multiply by Bhat[b][k2][k1]; inverse FFT over k1
// -> Z[k2][j]; * exp(+2*pi*i*k2*j/M); store [j][k2].

__global__ __launch_bounds__(256) void k2_mid(const float2* __restrict__ in,
                                              const float2* __restrict__ bhat,
                                              float2* __restrict__ out) {
    __shared__ float2 bufA[16 * LDSP];
    __shared__ float2 bufB[16 * LDSP];
    __shared__ float2 twd[64];
    int tid  = threadIdx.x;
    int row  = blockIdx.x >> 3;
    int b    = row >> 3;
    int k2_0 = (blockIdx.x & 7) << 4;
    const float2* rin = in + (size_t)row * Mm + ((size_t)k2_0 << 7);
    const float2* bh  = bhat + (size_t)b * Mm + ((size_t)k2_0 << 7);

    load_twiddle(twd, tid);
    #pragma unroll
    for (int lch = 0; lch < 8; ++lch) {
        int l = lch * 256 + tid;
        bufA[(l >> 7) * LDSP + (l & 127)] = rin[l];   // coalesced
    }
    int f = tid >> 4, lane = tid & 15;
    fft128_core<-1>(bufA, bufB, twd, f, lane);        // X in bufB

    // pointwise multiply by Bhat (same [k2][k1] layout), coalesced over k1
    #pragma unroll
    for (int lch = 0; lch < 8; ++lch) {
        int l = lch * 256 + tid;
        int i = l >> 7, k1 = l & 127;
        float2 v = bufB[i * LDSP + k1];
        float2 w = bh[l];
        bufB[i * LDSP + k1] = make_float2(v.x * w.x - v.y * w.y,
                                          v.x * w.y + v.y * w.x);
    }
    // (fft128_core starts with __syncthreads, covering the multiply)
    fft128_core<1>(bufB, bufA, twd, f, lane);         // Z in bufA

    float2* rout = out + (size_t)row * Mm;
    #pragma unroll
    for (int lch = 0; lch < 8; ++lch) {
        int l = lch * 256 + tid;
        int i = l & 15, j = l >> 4;
        float2 v = bufA[i * LDSP + j];
        int k2 = k2_0 + i;
        float ang = TWO_PI_F * (float)(k2 * j) * (1.0f / 16384.0f);
        float sw, cw;
        sincosf(ang, &sw, &cw);
        rout[(j << 7) + k2] = make_float2(v.x * cw - v.y * sw,
                                          v.x * sw + v.y * cw);
    }
}

// ---------------- K3: inverse pass2 + magnitude ----------------
// In: [j][k2]. FFT over k2 -> y[j + 128*w]; |.|/M for k<8192.

__global__ __launch_bounds__(256) void k3_final(const float2* __restrict__ in,
                                                float* __restrict__ outF) {
    __shared__ float2 bufA[16 * LDSP];
    __shared__ float2 bufB[16 * LDSP];
    __shared__ float2 twd[64];
    int tid  = threadIdx.x;
    int row  = blockIdx.x >> 3;
    int j_0  = (blockIdx.x & 7) << 4;
    const float2* rin = in + (size_t)row * Mm + ((size_t)j_0 << 7);

    load_twiddle(twd, tid);
    #pragma unroll
    for (int lch = 0; lch < 8; ++lch) {
        int l = lch * 256 + tid;
        bufA[(l >> 7) * LDSP + (l & 127)] = rin[l];
    }
    int f = tid >> 4, lane = tid & 15;
    fft128_core<1>(bufA, bufB, twd, f, lane);

    // y index k = (j_0 + i) + 128*w ; keep k < 8192  <=> w < 64
    int b = row >> 3, ch = row & 7;
    float* ob = outF + (size_t)b * Nn * Cc + ch;
    #pragma unroll
    for (int lch = 0; lch < 4; ++lch) {
        int l = lch * 256 + tid;
        int i = l & 15, w = l >> 4;       // w in [0,64)
        float2 v = bufB[i * LDSP + w];
        int k = (j_0 + i) + (w << 7);
        ob[(size_t)k * Cc] = sqrtf(v.x * v.x + v.y * v.y) * (1.0f / 16384.0f);
    }
}

// ---------------- launch ----------------

extern "C" void kernel_launch(void* const* d_in, const int* in_sizes, int n_in,
                              void* d_out, int out_size, void* d_ws, size_t ws_size,
                              hipStream_t stream) {
    const float* x   = (const float*)d_in[0];
    const float* rpm = (const float*)d_in[1];
    float* outF = (float*)d_out;

    float2* work1 = (float2*)d_ws;                  // 512*16384 float2 (64 MiB)
    float2* work2 = work1 + (size_t)ROWS * Mm;      // 512*16384 float2 (64 MiB)
    float2* bhat  = (float2*)d_out;                 // 64*16384 float2 (8 MiB), dead before K3

    // chirp prep: b -> Bhat (transposed spectral layout), parked in d_out
    chirp_pass1<<<Bn * 8, 256, 0, stream>>>(rpm, work1);
    chirp_pass2<<<Bn * 8, 256, 0, stream>>>(work1, bhat);

    // data: build+fft1 -> [k2][t1] ; fft2+mul+ifft1 -> [j][k2] ; ifft2+|.| -> out
    k1_build_fft<<<ROWS * 8, 256, 0, stream>>>(x, rpm, work1);
    k2_mid<<<ROWS * 8, 256, 0, stream>>>(work1, bhat, work2);
    k3_final<<<ROWS * 8, 256, 0, stream>>>(work2, outF);
}

// Round 3
// 91.278 us; speedup vs baseline: 1.6214x; 1.3773x over previous
//
#include <hip/hip_runtime.h>
#include <math.h>

// EngineOrderFFT via batched Bluestein. |X| = |conv[:, :K]| (final chirp is
// unit-modulus). M=16384 as four-step 128x128. Register-resident 128-pt FFT:
// 16 threads/FFT x 8 complex regs; DIF (natural->bitrev) forward, DIT
// (bitrev->natural) inverse; spectral multiply in bitrev domain => no
// bit-reversal passes anywhere. One LDS transpose per FFT + 1 shuffle stage.

static constexpr int Bn = 64;
static constexpr int Cc = 8;
static constexpr int Nn = 8192;
static constexpr int Mm = 16384;

#define PI_F 3.14159265358979323846f
#define TWO_PI_F 6.28318530717958647692f
#define R2_F 0.70710678118654752f

__device__ __forceinline__ int compute_n(float rpm) {
    // ref: pad = floor((40*60/rpm - 1)*8192) in f32; n = 8192 + pad
    return 8192 + (int)floorf((2400.0f / rpm - 1.0f) * 8192.0f);
}
__device__ __forceinline__ float2 cmul(float2 a, float2 b) {
    return make_float2(a.x*b.x - a.y*b.y, a.x*b.y + a.y*b.x);
}
__device__ __forceinline__ float2 cadd(float2 a, float2 b){ return make_float2(a.x+b.x, a.y+b.y); }
__device__ __forceinline__ float2 csub(float2 a, float2 b){ return make_float2(a.x-b.x, a.y-b.y); }
__device__ __forceinline__ float2 shflx1(float2 v) {
    return make_float2(__shfl_xor(v.x, 1, 64), __shfl_xor(v.y, 1, 64));
}

// DIF butterfly: lo=a+b ; hi=(a-b)*tw.   DIT: b'=b*tw ; lo=a+b' ; hi=a-b'.
#define BF(lo,hi,tw) { float2 _d = csub(lo,hi); lo = cadd(lo,hi); hi = cmul(_d, tw); }
#define BT(lo,hi,tw) { float2 _b = cmul(hi,tw); hi = csub(lo,_b); lo = cadd(lo,_b); }
#define SELC(r,c0,s0,c1,s1) ((r) ? make_float2(c1,s1) : make_float2(c0,s0))

// ---- forward 128-pt DIF. Input layout-A: v[q] = x[p+16q] (natural).
// Output layout-B: v[s] = x_final[j], j = 16*(p>>1)+(p&1)+2s  (= X[bitrev7(j)]).
// Lf: per-FFT LDS region, >=136 float2, stride-17 padded.
__device__ __forceinline__ void dif128(float2 v[8], float2* Lf, int p) {
    float sn, cs;
    __sincosf(PI_F * (float)p * (1.0f/64.0f), &sn, &cs);
    float2 w1 = make_float2(cs, -sn);          // W^-p
    float2 w2 = cmul(w1, w1);
    float2 w4 = cmul(w2, w2);
    // span 64: tw = W^-(p+16q) = w1 * e^{-i pi q/4}
    BF(v[0],v[4], w1);
    BF(v[1],v[5], cmul(w1, make_float2(R2_F,-R2_F)));
    BF(v[2],v[6], make_float2(w1.y, -w1.x));
    BF(v[3],v[7], cmul(w1, make_float2(-R2_F,-R2_F)));
    // span 32: tw = W^-2(p+16(q&1))
    float2 w2i = make_float2(w2.y, -w2.x);     // w2 * (-i)
    BF(v[0],v[2], w2);  BF(v[1],v[3], w2i);
    BF(v[4],v[6], w2);  BF(v[5],v[7], w2i);
    // span 16: tw = W^-4p
    BF(v[0],v[1], w4);  BF(v[2],v[3], w4);
    BF(v[4],v[5], w4);  BF(v[6],v[7], w4);
    // transpose: natural u=p+16q at lin addr u+(u>>4)
    __syncthreads();
    #pragma unroll
    for (int q = 0; q < 8; ++q) Lf[p + 17*q] = v[q];
    __syncthreads();
    int bb = p >> 1, r = p & 1;
    #pragma unroll
    for (int s = 0; s < 8; ++s) v[s] = Lf[17*bb + r + 2*s];
    // span 8: tw = e^{-i pi (r+2s)/8}
    BF(v[0],v[4], SELC(r, 1.f,0.f,                    0.92387953f,-0.38268343f));
    BF(v[1],v[5], SELC(r, 0.70710678f,-0.70710678f,   0.38268343f,-0.92387953f));
    BF(v[2],v[6], SELC(r, 0.f,-1.f,                  -0.38268343f,-0.92387953f));
    BF(v[3],v[7], SELC(r, -0.70710678f,-0.70710678f, -0.92387953f,-0.38268343f));
    // span 4: tw = e^{-i pi (r+2(s&1))/4}
    BF(v[0],v[2], SELC(r, 1.f,0.f,  0.70710678f,-0.70710678f));
    BF(v[1],v[3], SELC(r, 0.f,-1.f, -0.70710678f,-0.70710678f));
    BF(v[4],v[6], SELC(r, 1.f,0.f,  0.70710678f,-0.70710678f));
    BF(v[5],v[7], SELC(r, 0.f,-1.f, -0.70710678f,-0.70710678f));
    // span 2: tw = r ? -i : 1
    #pragma unroll
    for (int s = 0; s < 8; s += 2) {
        float2 d = csub(v[s], v[s+1]);
        v[s] = cadd(v[s], v[s+1]);
        v[s+1] = r ? make_float2(d.y, -d.x) : d;
    }
    // span 1: cross-thread (t ^ 1), tw = 1
    #pragma unroll
    for (int s = 0; s < 8; ++s) {
        float2 o = shflx1(v[s]);
        v[s] = r ? csub(o, v[s]) : cadd(v[s], o);
    }
}

// ---- inverse 128-pt DIT. Input layout-B: v[s] = y at bitrev-position
// j = 16*(p>>1)+(p&1)+2s (y[pos]=Y[bitrev(pos)]). Output layout-A natural:
// v[q] = z[p+16q], z[m] = sum_k Y[k] e^{+2 pi i k m/128} (unscaled).
__device__ __forceinline__ void dit128(float2 v[8], float2* Lf, int p) {
    int bb = p >> 1, r = p & 1;
    // span 1
    #pragma unroll
    for (int s = 0; s < 8; ++s) {
        float2 o = shflx1(v[s]);
        v[s] = r ? csub(o, v[s]) : cadd(v[s], o);
    }
    // span 2: tw = r ? +i : 1
    #pragma unroll
    for (int s = 0; s < 8; s += 2) {
        float2 b = v[s+1];
        if (r) b = make_float2(-b.y, b.x);
        v[s+1] = csub(v[s], b);
        v[s] = cadd(v[s], b);
    }
    // span 4: tw = e^{+i pi (r+2(s&1))/4}
    BT(v[0],v[2], SELC(r, 1.f,0.f,  0.70710678f,0.70710678f));
    BT(v[1],v[3], SELC(r, 0.f,1.f, -0.70710678f,0.70710678f));
    BT(v[4],v[6], SELC(r, 1.f,0.f,  0.70710678f,0.70710678f));
    BT(v[5],v[7], SELC(r, 0.f,1.f, -0.70710678f,0.70710678f));
    // span 8: tw = e^{+i pi (r+2s)/8}
    BT(v[0],v[4], SELC(r, 1.f,0.f,                   0.92387953f,0.38268343f));
    BT(v[1],v[5], SELC(r, 0.70710678f,0.70710678f,   0.38268343f,0.92387953f));
    BT(v[2],v[6], SELC(r, 0.f,1.f,                  -0.38268343f,0.92387953f));
    BT(v[3],v[7], SELC(r, -0.70710678f,0.70710678f, -0.92387953f,0.38268343f));
    // transpose back to layout-A
    __syncthreads();
    #pragma unroll
    for (int s = 0; s < 8; ++s) Lf[17*bb + r + 2*s] = v[s];
    __syncthreads();
    #pragma unroll
    for (int q = 0; q < 8; ++q) v[q] = Lf[p + 17*q];
    float sn, cs;
    __sincosf(PI_F * (float)p * (1.0f/64.0f), &sn, &cs);
    float2 w1 = make_float2(cs, sn);           // W^+p
    float2 w2 = cmul(w1, w1);
    float2 w4 = cmul(w2, w2);
    // span 16: tw = W^{+4p}
    BT(v[0],v[1], w4); BT(v[2],v[3], w4); BT(v[4],v[5], w4); BT(v[6],v[7], w4);
    // span 32
    float2 w2j = make_float2(-w2.y, w2.x);     // w2 * (+i)
    BT(v[0],v[2], w2);  BT(v[1],v[3], w2j);
    BT(v[4],v[6], w2);  BT(v[5],v[7], w2j);
    // span 64: tw = w1 * e^{+i pi q/4}
    BT(v[0],v[4], w1);
    BT(v[1],v[5], cmul(w1, make_float2(R2_F, R2_F)));
    BT(v[2],v[6], make_float2(-w1.y, w1.x));
    BT(v[3],v[7], cmul(w1, make_float2(-R2_F, R2_F)));
}

// ---------------- chirp pass 1: build b-chirp, DIF over t2, twiddle, -> [j][t1]
__global__ __launch_bounds__(256) void chirp_p1(const float* __restrict__ rpm,
                                                float2* __restrict__ w1c) {
    __shared__ float2 Lds[16*136];
    int tid = threadIdx.x;
    int f = tid >> 4, p = tid & 15;
    int b = blockIdx.x >> 3;
    int t1_0 = (blockIdx.x & 7) << 4;
    int t1 = t1_0 + f;
    int n = compute_n(rpm[b]);
    int two_n = 2*n;
    float inv_n = 1.0f/(float)n;
    float2 v[8];
    #pragma unroll
    for (int q = 0; q < 8; ++q) {
        int t = t1 + ((p + 16*q) << 7);
        int mm = min(t, Mm - t);
        int ph = (mm*mm) % two_n;
        float sn, cs;
        __sincosf(PI_F * (float)ph * inv_n, &sn, &cs);
        v[q] = make_float2(cs, sn);            // exp(+i b_phase)
    }
    dif128(v, Lds + f*136, p);
    int bb = p >> 1, r = p & 1;
    int slot = (f + 4*(bb & 3)) & 15;          // bank-balancing swizzle
    __syncthreads();
    #pragma unroll
    for (int s = 0; s < 8; ++s) Lds[(16*bb + r + 2*s)*17 + slot] = v[s];
    __syncthreads();
    float2* out = w1c + (size_t)b * Mm;
    #pragma unroll
    for (int it = 0; it < 8; ++it) {
        int l = it*256 + tid;
        int j = l >> 4, fr = l & 15;
        int sl = (fr + 4*((j >> 4) & 3)) & 15;
        float2 u = Lds[j*17 + sl];
        int k2 = __brev((unsigned)j) >> 25;    // actual frequency
        int t1r = t1_0 + fr;
        float sn, cs;
        __sincosf(-TWO_PI_F * (float)(t1r * k2) * (1.0f/16384.0f), &sn, &cs);
        out[(j << 7) + t1r] = cmul(u, make_float2(cs, sn));
    }
}

// ---------------- chirp pass 2: DIF over t1 -> Bhat in bitrev/register order
__global__ __launch_bounds__(256) void chirp_p2(const float2* __restrict__ w1c,
                                                float2* __restrict__ bhat) {
    __shared__ float2 Lds[16*136];
    int tid = threadIdx.x;
    int f = tid >> 4, p = tid & 15;
    int b = blockIdx.x >> 3;
    int l0 = (blockIdx.x & 7) << 4;
    const float2* in = w1c + (size_t)b * Mm + ((size_t)(l0 + f) << 7);
    float2 v[8];
    #pragma unroll
    for (int q = 0; q < 8; ++q) v[q] = in[p + 16*q];
    dif128(v, Lds + f*136, p);
    // store per-thread contiguous: bhat[b][row][p*8+s] holds bitrev-pos 16(p>>1)+(p&1)+2s
    float2* out = bhat + (size_t)b * Mm + ((size_t)(l0 + f) << 7) + p*8;
    #pragma unroll
    for (int s = 0; s < 8; ++s) out[s] = v[s];
}

// ---------------- K1: chirp-modulate x + DIF over t2 + twiddle -> [j][t1][ch]
__global__ __launch_bounds__(256) void k1(const float* __restrict__ x,
                                          const float* __restrict__ rpm,
                                          float2* __restrict__ w1g) {
    __shared__ float2 Lds[16*136];
    int tid = threadIdx.x;
    int f = tid >> 4, p = tid & 15;
    int b = blockIdx.x >> 6;
    int pr = blockIdx.x & 63;
    int t1_0 = pr << 1;
    int d = f >> 3, ch = f & 7;
    int t1 = t1_0 + d;
    int n = compute_n(rpm[b]);
    int two_n = 2*n;
    float inv_n = 1.0f/(float)n;
    const float* xb = x + (size_t)b * (Nn*Cc) + ch;
    float2 v[8];
    #pragma unroll
    for (int q = 0; q < 8; ++q) {
        int t = t1 + ((p + 16*q) << 7);
        if (t < Nn) {
            float xv = xb[(size_t)t * Cc];
            int ph = (t*t) % two_n;
            float sn, cs;
            __sincosf(PI_F * (float)ph * inv_n, &sn, &cs);
            v[q] = make_float2(xv*cs, -xv*sn); // x * exp(-i a_phase)
        } else {
            v[q] = make_float2(0.f, 0.f);
        }
    }
    dif128(v, Lds + f*136, p);
    int bb = p >> 1, r = p & 1;
    int slot = (f + 4*(bb & 3)) & 15;
    __syncthreads();
    #pragma unroll
    for (int s = 0; s < 8; ++s) Lds[(16*bb + r + 2*s)*17 + slot] = v[s];
    __syncthreads();
    // w1g[b][j][t1][ch] (float2): b*131072 + j*1024 + t1*8 + ch
    float2* out = w1g + (size_t)b * 131072 + t1_0*8;
    #pragma unroll
    for (int it = 0; it < 8; ++it) {
        int l = it*256 + tid;
        int j = l >> 4, fr = l & 15;
        int sl = (fr + 4*((j >> 4) & 3)) & 15;
        float2 u = Lds[j*17 + sl];
        int k2 = __brev((unsigned)j) >> 25;
        int t1r = t1_0 + (fr >> 3);
        float sn, cs;
        __sincosf(-TWO_PI_F * (float)(t1r * k2) * (1.0f/16384.0f), &sn, &cs);
        out[(size_t)j*1024 + fr] = cmul(u, make_float2(cs, sn));
    }
}

// ---------------- K2: DIF over t1, * Bhat (bitrev domain), DIT over k1,
// twiddle e^{+2pi i k2 j/M}, -> S2[b][j][c][ch]
__global__ __launch_bounds__(256) void k2(const float2* __restrict__ w1g,
                                          const float2* __restrict__ bhat,
                                          float2* __restrict__ s2) {
    __shared__ float2 Lds[16*136];
    int tid = threadIdx.x;
    int f = tid >> 4, p = tid & 15;
    int b = blockIdx.x >> 6;
    int pr = blockIdx.x & 63;
    int l0 = pr << 1;
    int d = f >> 3, ch = f & 7;
    int row = l0 + d;
    const float2* in = w1g + (size_t)b * 131072 + (size_t)row * 1024 + ch;
    float2 v[8];
    #pragma unroll
    for (int q = 0; q < 8; ++q) v[q] = in[(p + 16*q) * 8];
    dif128(v, Lds + f*136, p);
    const float2* bh = bhat + (size_t)b * Mm + ((size_t)row << 7) + p*8;
    #pragma unroll
    for (int s = 0; s < 8; ++s) v[s] = cmul(v[s], bh[s]);
    dit128(v, Lds + f*136, p);
    int k2a = __brev((unsigned)row) >> 25;     // actual k2 of this row
    #pragma unroll
    for (int q = 0; q < 8; ++q) {
        int j = p + 16*q;
        float sn, cs;
        __sincosf(TWO_PI_F * (float)(k2a * j) * (1.0f/16384.0f), &sn, &cs);
        v[q] = cmul(v[q], make_float2(cs, sn));
    }
    __syncthreads();
    #pragma unroll
    for (int q = 0; q < 8; ++q) Lds[(p + 16*q)*17 + f] = v[q];
    __syncthreads();
    // c(row=l0+dr) = (l0>>4)*16 + dr*8 + ((l0>>1)&7)
    int cbase = ((l0 >> 4) << 4) + ((l0 >> 1) & 7);
    float2* out = s2 + (size_t)b * 131072 + cbase*8;
    #pragma unroll
    for (int it = 0; it < 8; ++it) {
        int l = it*256 + tid;
        int j = l >> 4, fr = l & 15;
        float2 u = Lds[j*17 + fr];
        int dr = fr >> 3, chr = fr & 7;
        out[(size_t)j*1024 + dr*64 + chr] = u;
    }
}

// ---------------- K3: DIT over k2 (input already bitrev-ordered) + |.|/M
__global__ __launch_bounds__(256) void k3(const float2* __restrict__ s2,
                                          float* __restrict__ outF) {
    __shared__ float2 Lds[16*136];
    int tid = threadIdx.x;
    int f = tid >> 4, p = tid & 15;
    int b = blockIdx.x >> 6;
    int pr = blockIdx.x & 63;
    int j0 = pr << 1;
    int jd = f >> 3, ch = f & 7;
    int j = j0 + jd;
    const float2* in = s2 + (size_t)b * 131072 + (size_t)j * 1024 + p*64 + ch;
    float2 v[8];
    #pragma unroll
    for (int s = 0; s < 8; ++s) v[s] = in[s*8];
    dit128(v, Lds + f*136, p);
    // v[q] = z[m = j + 128*(p+16q)]; keep w = p+16q < 64 => q < 4
    float* ob = outF + ((size_t)b * Nn + j) * Cc + ch;
    #pragma unroll
    for (int q = 0; q < 4; ++q) {
        int w = p + 16*q;
        float2 z = v[q];
        ob[(size_t)w * 1024] = sqrtf(z.x*z.x + z.y*z.y) * (1.0f/16384.0f);
    }
}

// ---------------- launch ----------------
extern "C" void kernel_launch(void* const* d_in, const int* in_sizes, int n_in,
                              void* d_out, int out_size, void* d_ws, size_t ws_size,
                              hipStream_t stream) {
    const float* x   = (const float*)d_in[0];
    const float* rpm = (const float*)d_in[1];
    float* outF = (float*)d_out;

    float2* w1c  = (float2*)d_ws;                           // 8 MB (reused by w1g)
    float2* w1g  = (float2*)d_ws;                           // 64 MB
    float2* s2   = (float2*)d_ws + (size_t)Bn * 131072;     // 64 MB
    float2* bhat = (float2*)d_out;                          // 8 MB, dead before k3

    chirp_p1<<<Bn*8,  256, 0, stream>>>(rpm, w1c);
    chirp_p2<<<Bn*8,  256, 0, stream>>>(w1c, bhat);
    k1<<<Bn*64, 256, 0, stream>>>(x, rpm, w1g);
    k2<<<Bn*64, 256, 0, stream>>>(w1g, bhat, s2);
    k3<<<Bn*64, 256, 0, stream>>>(s2, outF);
}